// Round 1
// baseline (268.824 us; speedup 1.0000x reference)
//
#include <hip/hip_runtime.h>

// ---------------- problem constants ----------------
#define BATCH     16
#define T_LEN     480000
#define PAD       512
#define TPAD      481024      // T_LEN + 2*PAD
#define HOP       256
#define NFFT      1024
#define NFRAMES   1876        // (TPAD - NFFT)/HOP + 1
#define M_TOTAL   30016       // BATCH*NFRAMES
#define NOUTROW   1026        // 513 freqs * 2 (re,im interleaved)
#define KTOT      1024

// ---------------- GEMM tile config ----------------
#define BM        128
#define BN        128
#define BK        32

typedef __attribute__((ext_vector_type(8))) short short8;
typedef __attribute__((ext_vector_type(4))) float floatx4;

__device__ __forceinline__ unsigned short f2bf(float f) {
  union { float f; unsigned int u; } v; v.f = f;
  unsigned int u = v.u;
  return (unsigned short)((u + 0x7FFFu + ((u >> 16) & 1u)) >> 16); // RNE
}
__device__ __forceinline__ float bf2f(unsigned short h) {
  union { unsigned int u; float f; } v; v.u = ((unsigned int)h) << 16;
  return v.f;
}

// Stage reflect-padded signal as bf16: xp[b][i], i in [0,TPAD)
__global__ __launch_bounds__(256) void build_xp(const float* __restrict__ x,
                                                unsigned short* __restrict__ xp) {
  const int i = blockIdx.x * 256 + threadIdx.x;   // [0, TPAD)
  const int b = blockIdx.y;
  int j = i - PAD;
  if (j < 0) j = -j;                               // left reflect
  if (j >= T_LEN) j = 2 * T_LEN - 2 - j;           // right reflect
  xp[(size_t)b * TPAD + i] = f2bf(x[(size_t)b * T_LEN + j]);
}

// Basis matrix, transposed for B-operand staging: bmat[jcol][k], jcol in [0,1024)
// jcol = 2f   -> cos(2*pi/1024 * f * k) * w[k]
// jcol = 2f+1 -> -sin(2*pi/1024 * f * k) * w[k]
__global__ __launch_bounds__(256) void build_bmat(const float* __restrict__ win,
                                                  unsigned short* __restrict__ bm) {
  const int k = blockIdx.x * 256 + threadIdx.x;   // [0,1024)
  const int j = blockIdx.y;                       // [0,1024)
  const int f = j >> 1;
  const int r = (f * k) & (NFFT - 1);             // exact arg reduction (f*k < 2^24)
  const float ang = (float)r * 6.1359231515e-3f;  // 2*pi/1024
  const float c = __cosf(ang), s = __sinf(ang);
  const float v = (j & 1) ? -s : c;
  bm[(size_t)j * KTOT + k] = f2bf(v * win[k]);
}

// GEMM: C[m][j] = sum_k A[m][k]*B[k][j],  A[m][k]=xp[b(m)][t(m)*HOP+k],
// B[k][j]=bmat[j][k].  Output interleaved row stride NOUTROW.
__global__ __launch_bounds__(256) void stft_gemm(const unsigned short* __restrict__ xp,
                                                 const unsigned short* __restrict__ bmat,
                                                 float* __restrict__ out) {
  // LDS tiles, both [row][BK], 16B-chunk XOR swizzle: chunk slot = c ^ (row&3)
  __shared__ unsigned short As[BM * BK];
  __shared__ unsigned short Bs[BN * BK];

  const int tid  = threadIdx.x;
  const int lane = tid & 63;
  const int wv   = tid >> 6;
  const int wr   = wv >> 1, wc = wv & 1;        // 2x2 waves over 128x128
  const int m0   = blockIdx.x * BM;
  const int j0   = blockIdx.y * BN;
  const int L    = lane & 15;
  const int quad = lane >> 4;

  // staging sources: chunk ci = p*256 + tid covers LDS bytes [ci*16, ci*16+16)
  // row = ci>>2, slot = ci&3, logical k-chunk c = slot ^ (row&3)
  const unsigned short* agsrc[2];
  const unsigned short* bgsrc[2];
#pragma unroll
  for (int p = 0; p < 2; ++p) {
    const int ci = p * 256 + tid;
    const int row = ci >> 2;
    const int c   = (ci & 3) ^ (row & 3);
    int gm = m0 + row; if (gm > M_TOTAL - 1) gm = M_TOTAL - 1;   // clamp tail rows
    const int bb = gm / NFRAMES;
    const int tt = gm - bb * NFRAMES;
    agsrc[p] = xp   + (size_t)bb * TPAD + (size_t)tt * HOP + c * 8;
    bgsrc[p] = bmat + (size_t)(j0 + row) * KTOT + c * 8;
  }

  floatx4 acc[4][4] = {};

  for (int k0 = 0; k0 < KTOT; k0 += BK) {
#pragma unroll
    for (int p = 0; p < 2; ++p) {
      const int ci = p * 256 + tid;
      __builtin_amdgcn_global_load_lds(
          (const __attribute__((address_space(1))) void*)(agsrc[p] + k0),
          (__attribute__((address_space(3))) void*)((char*)As + ci * 16),
          16, 0, 0);
      __builtin_amdgcn_global_load_lds(
          (const __attribute__((address_space(1))) void*)(bgsrc[p] + k0),
          (__attribute__((address_space(3))) void*)((char*)Bs + ci * 16),
          16, 0, 0);
    }
    __syncthreads();

    short8 af[4], bfv[4];
#pragma unroll
    for (int t = 0; t < 4; ++t) {
      const int m = wr * 64 + t * 16 + L;              // A row
      const int ca = quad ^ (m & 3);
      af[t] = *(const short8*)&As[m * BK + ca * 8];
      const int n = wc * 64 + t * 16 + L;              // B col
      const int cb = quad ^ (n & 3);
      bfv[t] = *(const short8*)&Bs[n * BK + cb * 8];
    }
#pragma unroll
    for (int ti = 0; ti < 4; ++ti)
#pragma unroll
      for (int tj = 0; tj < 4; ++tj)
        acc[ti][tj] = __builtin_amdgcn_mfma_f32_16x16x32_bf16(
            af[ti], bfv[tj], acc[ti][tj], 0, 0, 0);
    __syncthreads();
  }

  // epilogue: D[row = quad*4 + i][col = L] per 16x16 tile
#pragma unroll
  for (int ti = 0; ti < 4; ++ti) {
    const int gmb = m0 + wr * 64 + ti * 16 + quad * 4;
#pragma unroll
    for (int tj = 0; tj < 4; ++tj) {
      const int gj = j0 + wc * 64 + tj * 16 + L;       // < 1024 always
#pragma unroll
      for (int i = 0; i < 4; ++i) {
        const int gm = gmb + i;
        if (gm < M_TOTAL) out[(size_t)gm * NOUTROW + gj] = acc[ti][tj][i];
      }
    }
  }
}

// Nyquist column: out[m][1024] = sum_n (-1)^n w[n] frame_m[n]; out[m][1025] = 0
__global__ __launch_bounds__(256) void nyq_kernel(const unsigned short* __restrict__ xp,
                                                  const float* __restrict__ win,
                                                  float* __restrict__ out) {
  const int gwave = blockIdx.x * 4 + (threadIdx.x >> 6);   // one wave per row m
  const int lane  = threadIdx.x & 63;
  const int b = gwave / NFRAMES;
  const int t = gwave - b * NFRAMES;
  const unsigned short* src = xp + (size_t)b * TPAD + (size_t)t * HOP;
  float sum = 0.f;
#pragma unroll
  for (int i = 0; i < 4; ++i) {
    const int e0 = (i * 64 + lane) * 4;   // 4 consecutive elems, e0 even
    const ushort4 xv = *(const ushort4*)(src + e0);
    const float4  wv = *(const float4*)(win + e0);
    sum += wv.x * bf2f(xv.x) - wv.y * bf2f(xv.y)
         + wv.z * bf2f(xv.z) - wv.w * bf2f(xv.w);
  }
#pragma unroll
  for (int off = 32; off > 0; off >>= 1) sum += __shfl_down(sum, off);
  if (lane == 0) {
    out[(size_t)gwave * NOUTROW + 1024] = sum;
    out[(size_t)gwave * NOUTROW + 1025] = 0.f;
  }
}

extern "C" void kernel_launch(void* const* d_in, const int* in_sizes, int n_in,
                              void* d_out, int out_size, void* d_ws, size_t ws_size,
                              hipStream_t stream) {
  const float* x   = (const float*)d_in[0];   // (16, 480000) fp32
  const float* win = (const float*)d_in[1];   // (1024,) fp32
  float* out = (float*)d_out;                 // (16, 1876, 513, 2) fp32

  unsigned short* xp   = (unsigned short*)d_ws;                  // 16*481024 bf16 = 15.4 MB
  unsigned short* bmat = xp + (size_t)BATCH * TPAD;              // 1024*1024 bf16 = 2 MB

  build_xp  <<<dim3(TPAD / 256, BATCH), 256, 0, stream>>>(x, xp);
  build_bmat<<<dim3(KTOT / 256, 1024),  256, 0, stream>>>(win, bmat);
  stft_gemm <<<dim3((M_TOTAL + BM - 1) / BM, 1024 / BN), 256, 0, stream>>>(xp, bmat, out);
  nyq_kernel<<<M_TOTAL / 4, 256, 0, stream>>>(xp, win, out);
}

// Round 2
// 250.690 us; speedup vs baseline: 1.0723x; 1.0723x over previous
//
#include <hip/hip_runtime.h>

// ---------------- problem constants ----------------
#define BATCH     16
#define T_LEN     480000
#define PAD       512
#define TPAD      481024      // T_LEN + 2*PAD
#define HOP       256
#define NFRAMES   1876        // (TPAD - NFFT)/HOP + 1
#define FRPAD     1920        // frames padded to 15 blocks of 128 per batch
#define NOUTROW   1026        // 513 freqs * 2 (re,im interleaved)
#define KTOT      1024
#define NCOLS     1152        // padded B columns: 9 tiles of 128 (cols >=1026 are zero)

// ---------------- GEMM tile config ----------------
#define BM        128
#define BN        128
#define BK        32
#define ACH       4352        // A chunks (16B) staged per block = 69632 B LDS
                              //   covers (128-1)*256+1024 = 33536 samples (4192 ch) + pad
#define XPSTRIDE  493568      // padded xp row stride: 1792*256 + ACH*8  (256-divisible)

typedef __attribute__((ext_vector_type(8))) short short8;
typedef __attribute__((ext_vector_type(4))) float floatx4;

__device__ __forceinline__ unsigned short f2bf(float f) {
  union { float f; unsigned int u; } v; v.f = f;
  unsigned int u = v.u;
  return (unsigned short)((u + 0x7FFFu + ((u >> 16) & 1u)) >> 16); // RNE
}

// Reflect-padded signal as bf16, row stride XPSTRIDE, tail zero-filled.
__global__ __launch_bounds__(256) void build_xp(const float* __restrict__ x,
                                                unsigned short* __restrict__ xp) {
  const int i = blockIdx.x * 256 + threadIdx.x;   // [0, XPSTRIDE)
  const int b = blockIdx.y;
  unsigned short v = 0;
  if (i < TPAD) {
    int j = i - PAD;
    if (j < 0) j = -j;                             // left reflect
    if (j >= T_LEN) j = 2 * T_LEN - 2 - j;         // right reflect
    v = f2bf(x[(size_t)b * T_LEN + j]);
  }
  xp[(size_t)b * XPSTRIDE + i] = v;
}

// Basis matrix bmat[jcol][k], jcol in [0,1152):
//   jcol = 2f   -> cos(2*pi/1024 * f * k) * w[k]
//   jcol = 2f+1 -> -sin(2*pi/1024 * f * k) * w[k]
// jcol=1024/1025 fall out exactly (f=512 -> (-1)^k, 0); jcol>=1026 -> 0.
__global__ __launch_bounds__(256) void build_bmat(const float* __restrict__ win,
                                                  unsigned short* __restrict__ bm) {
  const int k = blockIdx.x * 256 + threadIdx.x;   // [0,1024)
  const int j = blockIdx.y;                       // [0,1152)
  unsigned short o = 0;
  if (j < NOUTROW) {
    const int f = j >> 1;
    const int r = (f * k) & (KTOT - 1);           // exact arg reduction
    const float ang = (float)r * 6.1359231515e-3f;  // 2*pi/1024
    const float c = __cosf(ang), s = __sinf(ang);
    const float v = (j & 1) ? -s : c;
    o = f2bf(v * win[k]);
  }
  bm[(size_t)j * KTOT + k] = o;
}

// C[m][j] = sum_k xp[b][t*HOP + k] * bmat[j][k]
// A staged ONCE per block (contiguous signal window, XOR chunk swizzle);
// B staged per k-iter (single buffer).
__global__ __launch_bounds__(256, 2) void stft_gemm(const unsigned short* __restrict__ xp,
                                                    const unsigned short* __restrict__ bmat,
                                                    float* __restrict__ out) {
  __shared__ unsigned short As[ACH * 8];   // 69632 B: swizzled signal window
  __shared__ unsigned short Bs[BN * BK];   // 8192 B: [col][32k], m97-style

  const int tid  = threadIdx.x;
  const int lane = tid & 63;
  const int wv   = tid >> 6;
  const int wr   = wv >> 1, wc = wv & 1;   // 2x2 waves over 128x128
  const int bx   = blockIdx.x;             // [0,240)
  const int b    = bx / 15;
  const int t0   = (bx - b * 15) * BM;     // frame base, <=1792
  const int j0   = blockIdx.y * BN;        // [0,1152) step 128
  const int L    = lane & 15;
  const int quad = lane >> 4;

  const unsigned short* abase = xp + (size_t)b * XPSTRIDE + (size_t)t0 * HOP;

  // ---- stage A once: LDS chunk ci <- global chunk perm(ci) (involution) ----
#pragma unroll
  for (int r = 0; r < ACH / 256; ++r) {
    const int ci = r * 256 + tid;
    const int s  = ci ^ ((ci >> 5) & 7);
    __builtin_amdgcn_global_load_lds(
        (const __attribute__((address_space(1))) void*)(abase + s * 8),
        (__attribute__((address_space(3))) void*)((char*)As + ci * 16),
        16, 0, 0);
  }

  // B staging sources: 2 chunks/thread/iter
  const unsigned short* bsrc[2];
#pragma unroll
  for (int p = 0; p < 2; ++p) {
    const int ci  = p * 256 + tid;
    const int col = ci >> 2, c = ci & 3;
    bsrc[p] = bmat + (size_t)(j0 + col) * KTOT + c * 8;
  }

  // Fragment address bases
  int sbase[4];                      // A: sample-chunk = 32*ml + quad (+ k0/8)
  const unsigned short* blds[4];     // B: fixed LDS addrs
#pragma unroll
  for (int t = 0; t < 4; ++t) {
    const int ml = wr * 64 + t * 16 + L;
    sbase[t] = 32 * ml + quad;
    const int n = wc * 64 + t * 16 + L;
    blds[t] = &Bs[n * BK + quad * 8];
  }

  floatx4 acc[4][4] = {};

  for (int k0 = 0; k0 < KTOT; k0 += BK) {
#pragma unroll
    for (int p = 0; p < 2; ++p) {
      const int ci = p * 256 + tid;
      __builtin_amdgcn_global_load_lds(
          (const __attribute__((address_space(1))) void*)(bsrc[p] + k0),
          (__attribute__((address_space(3))) void*)((char*)Bs + ci * 16),
          16, 0, 0);
    }
    __syncthreads();   // drains B loads (and A loads on iter 0)

    short8 af[4], bf[4];
    const int kc = k0 >> 3;
#pragma unroll
    for (int t = 0; t < 4; ++t) {
      const int s = sbase[t] + kc;
      const int p = s ^ ((s >> 5) & 7);
      af[t] = *(const short8*)&As[p * 8];
      bf[t] = *(const short8*)blds[t];
    }
#pragma unroll
    for (int ti = 0; ti < 4; ++ti)
#pragma unroll
      for (int tj = 0; tj < 4; ++tj)
        acc[ti][tj] = __builtin_amdgcn_mfma_f32_16x16x32_bf16(
            af[ti], bf[tj], acc[ti][tj], 0, 0, 0);
    __syncthreads();   // protect Bs before next iter's overwrite
  }

  // ---- epilogue: D[row = quad*4 + i][col = L] per 16x16 tile ----
#pragma unroll
  for (int ti = 0; ti < 4; ++ti) {
    const int tb = t0 + wr * 64 + ti * 16 + quad * 4;
#pragma unroll
    for (int tj = 0; tj < 4; ++tj) {
      const int gj = j0 + wc * 64 + tj * 16 + L;
      if (gj < NOUTROW) {
#pragma unroll
        for (int i = 0; i < 4; ++i) {
          const int t = tb + i;
          if (t < NFRAMES)
            out[(size_t)(b * NFRAMES + t) * NOUTROW + gj] = acc[ti][tj][i];
        }
      }
    }
  }
}

extern "C" void kernel_launch(void* const* d_in, const int* in_sizes, int n_in,
                              void* d_out, int out_size, void* d_ws, size_t ws_size,
                              hipStream_t stream) {
  const float* x   = (const float*)d_in[0];   // (16, 480000) fp32
  const float* win = (const float*)d_in[1];   // (1024,) fp32
  float* out = (float*)d_out;                 // (16, 1876, 513, 2) fp32

  unsigned short* xp   = (unsigned short*)d_ws;                  // 16*493568 bf16 = 15.8 MB
  unsigned short* bmat = xp + (size_t)BATCH * XPSTRIDE;          // 1152*1024 bf16 = 2.36 MB

  build_xp  <<<dim3(XPSTRIDE / 256, BATCH), 256, 0, stream>>>(x, xp);
  build_bmat<<<dim3(KTOT / 256, NCOLS),     256, 0, stream>>>(win, bmat);
  stft_gemm <<<dim3(BATCH * (FRPAD / BM), NCOLS / BN), 256, 0, stream>>>(xp, bmat, out);
}

// Round 3
// 238.485 us; speedup vs baseline: 1.1272x; 1.0512x over previous
//
#include <hip/hip_runtime.h>

// ---------------- problem constants ----------------
#define BATCH     16
#define T_LEN     480000
#define PAD       512
#define TPAD      481024      // T_LEN + 2*PAD
#define HOP       256
#define NFRAMES   1876        // (TPAD - NFFT)/HOP + 1
#define FRPAD     1920        // frames padded to 15 blocks of 128 per batch
#define NOUTROW   1026        // 513 freqs * 2 (re,im interleaved)
#define KTOT      1024
#define NCOLS     1152        // padded B columns: 9 tiles of 128 (cols >=1026 are zero)

// ---------------- GEMM tile config ----------------
#define BM        128
#define BN        128
#define BK        32
#define ACH       4352        // A chunks (16B) staged per block = 69632 B LDS
#define XPSTRIDE  493568      // padded xp row stride: 1792*256 + ACH*8  (256-divisible)

typedef __attribute__((ext_vector_type(8))) short short8;
typedef __attribute__((ext_vector_type(4))) float floatx4;

__device__ __forceinline__ unsigned short f2bf(float f) {
  union { float f; unsigned int u; } v; v.f = f;
  unsigned int u = v.u;
  return (unsigned short)((u + 0x7FFFu + ((u >> 16) & 1u)) >> 16); // RNE
}

// Reflect-padded signal as bf16, row stride XPSTRIDE, tail zero-filled.
__global__ __launch_bounds__(256) void build_xp(const float* __restrict__ x,
                                                unsigned short* __restrict__ xp) {
  const int i = blockIdx.x * 256 + threadIdx.x;   // [0, XPSTRIDE)
  const int b = blockIdx.y;
  unsigned short v = 0;
  if (i < TPAD) {
    int j = i - PAD;
    if (j < 0) j = -j;                             // left reflect
    if (j >= T_LEN) j = 2 * T_LEN - 2 - j;         // right reflect
    v = f2bf(x[(size_t)b * T_LEN + j]);
  }
  xp[(size_t)b * XPSTRIDE + i] = v;
}

// Basis matrix bmat[jcol][k], jcol in [0,1152):
//   jcol = 2f   -> cos(2*pi/1024 * f * k) * w[k]
//   jcol = 2f+1 -> -sin(2*pi/1024 * f * k) * w[k]
// jcol=1024/1025 fall out exactly (f=512 -> (-1)^k, 0); jcol>=1026 -> 0.
__global__ __launch_bounds__(256) void build_bmat(const float* __restrict__ win,
                                                  unsigned short* __restrict__ bm) {
  const int k = blockIdx.x * 256 + threadIdx.x;   // [0,1024)
  const int j = blockIdx.y;                       // [0,1152)
  unsigned short o = 0;
  if (j < NOUTROW) {
    const int f = j >> 1;
    const int r = (f * k) & (KTOT - 1);           // exact arg reduction
    const float ang = (float)r * 6.1359231515e-3f;  // 2*pi/1024
    const float c = __cosf(ang), s = __sinf(ang);
    const float v = (j & 1) ? -s : c;
    o = f2bf(v * win[k]);
  }
  bm[(size_t)j * KTOT + k] = o;
}

// C[m][j] = sum_k xp[b][t*HOP + k] * bmat[j][k]
// A staged ONCE per block; B double-buffered through REGISTERS:
//   iter k: issue global->reg load of B(k+1); MFMA on Bs(k) [load latency
//   hides under ~310 cyc of MFMA]; barrier; ds_write reg->Bs; barrier.
__global__ __launch_bounds__(256, 2) void stft_gemm(const unsigned short* __restrict__ xp,
                                                    const unsigned short* __restrict__ bmat,
                                                    float* __restrict__ out) {
  __shared__ unsigned short As[ACH * 8];   // 69632 B: swizzled signal window
  __shared__ unsigned short Bs[BN * BK];   // 8192 B: [col][32k]

  const int tid  = threadIdx.x;
  const int lane = tid & 63;
  const int wv   = tid >> 6;
  const int wr   = wv >> 1, wc = wv & 1;   // 2x2 waves over 128x128
  const int bx   = blockIdx.x;             // [0,240)
  const int b    = bx / 15;
  const int t0   = (bx - b * 15) * BM;     // frame base, <=1792
  const int j0   = blockIdx.y * BN;        // [0,1152) step 128
  const int L    = lane & 15;
  const int quad = lane >> 4;

  const unsigned short* abase = xp + (size_t)b * XPSTRIDE + (size_t)t0 * HOP;

  // ---- stage A once: LDS chunk ci <- global chunk perm(ci) (involution) ----
#pragma unroll
  for (int r = 0; r < ACH / 256; ++r) {
    const int ci = r * 256 + tid;
    const int s  = ci ^ ((ci >> 5) & 7);
    __builtin_amdgcn_global_load_lds(
        (const __attribute__((address_space(1))) void*)(abase + s * 8),
        (__attribute__((address_space(3))) void*)((char*)As + ci * 16),
        16, 0, 0);
  }

  // B staging: thread owns chunks ci = p*256+tid -> Bs bytes [ci*16, ci*16+16)
  // global source: col = ci>>2, kchunk = ci&3
  const unsigned short* bsrc[2];
  short8* blds_w[2];
#pragma unroll
  for (int p = 0; p < 2; ++p) {
    const int ci  = p * 256 + tid;
    const int col = ci >> 2, c = ci & 3;
    bsrc[p]   = bmat + (size_t)(j0 + col) * KTOT + c * 8;
    blds_w[p] = (short8*)&Bs[ci * 8];   // ci*16 bytes
  }

  // Fragment address bases
  int sbase[4];                      // A: sample-chunk = 32*ml + quad (+ k0/8)
  const unsigned short* blds[4];     // B: fixed LDS addrs
#pragma unroll
  for (int t = 0; t < 4; ++t) {
    const int ml = wr * 64 + t * 16 + L;
    sbase[t] = 32 * ml + quad;
    const int n = wc * 64 + t * 16 + L;
    blds[t] = &Bs[n * BK + quad * 8];
  }

  // ---- preload B(k0=0) via registers, park in LDS ----
  short8 breg[2];
#pragma unroll
  for (int p = 0; p < 2; ++p) breg[p] = *(const short8*)bsrc[p];
  // (first barrier below also drains the A global_load_lds)
  __syncthreads();                    // actually needed before first ds_write? No LDS
                                      // readers yet, but A-lds loads must complete
                                      // before any frag read; keep one here so the
                                      // ds_write + next barrier suffice for B.
#pragma unroll
  for (int p = 0; p < 2; ++p) *blds_w[p] = breg[p];
  __syncthreads();

  floatx4 acc[4][4] = {};

  for (int k0 = 0; k0 < KTOT; k0 += BK) {
    // issue next-iter B loads first: latency hides under the MFMAs below
    const bool more = (k0 + BK) < KTOT;
    if (more) {
#pragma unroll
      for (int p = 0; p < 2; ++p) breg[p] = *(const short8*)(bsrc[p] + k0 + BK);
    }

    short8 af[4], bf[4];
    const int kc = k0 >> 3;
#pragma unroll
    for (int t = 0; t < 4; ++t) {
      const int s = sbase[t] + kc;
      const int p = s ^ ((s >> 5) & 7);
      af[t] = *(const short8*)&As[p * 8];
      bf[t] = *(const short8*)blds[t];
    }
#pragma unroll
    for (int ti = 0; ti < 4; ++ti)
#pragma unroll
      for (int tj = 0; tj < 4; ++tj)
        acc[ti][tj] = __builtin_amdgcn_mfma_f32_16x16x32_bf16(
            af[ti], bf[tj], acc[ti][tj], 0, 0, 0);

    if (more) {
      __syncthreads();                 // all waves done reading Bs(k0)
#pragma unroll
      for (int p = 0; p < 2; ++p) *blds_w[p] = breg[p];
      __syncthreads();                 // Bs(k0+BK) visible to all
    }
  }

  // ---- epilogue: D[row = quad*4 + i][col = L] per 16x16 tile ----
#pragma unroll
  for (int ti = 0; ti < 4; ++ti) {
    const int tb = t0 + wr * 64 + ti * 16 + quad * 4;
#pragma unroll
    for (int tj = 0; tj < 4; ++tj) {
      const int gj = j0 + wc * 64 + tj * 16 + L;
      if (gj < NOUTROW) {
#pragma unroll
        for (int i = 0; i < 4; ++i) {
          const int t = tb + i;
          if (t < NFRAMES)
            out[(size_t)(b * NFRAMES + t) * NOUTROW + gj] = acc[ti][tj][i];
        }
      }
    }
  }
}

extern "C" void kernel_launch(void* const* d_in, const int* in_sizes, int n_in,
                              void* d_out, int out_size, void* d_ws, size_t ws_size,
                              hipStream_t stream) {
  const float* x   = (const float*)d_in[0];   // (16, 480000) fp32
  const float* win = (const float*)d_in[1];   // (1024,) fp32
  float* out = (float*)d_out;                 // (16, 1876, 513, 2) fp32

  unsigned short* xp   = (unsigned short*)d_ws;                  // 16*493568 bf16 = 15.8 MB
  unsigned short* bmat = xp + (size_t)BATCH * XPSTRIDE;          // 1152*1024 bf16 = 2.36 MB

  build_xp  <<<dim3(XPSTRIDE / 256, BATCH), 256, 0, stream>>>(x, xp);
  build_bmat<<<dim3(KTOT / 256, NCOLS),     256, 0, stream>>>(win, bmat);
  stft_gemm <<<dim3(BATCH * (FRPAD / BM), NCOLS / BN), 256, 0, stream>>>(xp, bmat, out);
}